// Round 1
// baseline (444.255 us; speedup 1.0000x reference)
//
#include <hip/hip_runtime.h>
#include <hip/hip_fp16.h>

typedef _Float16 f16;
typedef __attribute__((ext_vector_type(8))) _Float16 f16x8;
typedef __attribute__((ext_vector_type(4))) _Float16 f16x4;
typedef __attribute__((ext_vector_type(4))) float f32x4;

#define MFMA16(a, b, c) __builtin_amdgcn_mfma_f32_16x16x32_f16((a), (b), (c), 0, 0, 0)

// ---------------- workspace layout (bytes) ----------------
#define OFF_WK   0u              // w_k folded, f16 [256][256]   (128 KB)
#define OFF_WS   131072u         // w_s folded, f16 [256][256]
#define OFF_WH1  262144u         // w_h1 folded, f16 [256][256]
#define OFF_SH   393216u         // shifts f32 [3][256]
#define OFF_S    409600u         // s  f16 [128*961][256] (62,980,096 B) ; reused as y [80000][256]
#define OFF_KF   63389696u       // k_feat f16 [128*49][256] (3,211,264 B)
#define OFF_FEAT 66600960u       // feat f16 [128*625][256] (40,960,000 B)

// ---------------- weight prep: fold BN scale, convert to f16 ----------------
__global__ __launch_bounds__(256) void prep_weights(
    const float* __restrict__ wk, const float* __restrict__ gk, const float* __restrict__ bk,
    const float* __restrict__ mk, const float* __restrict__ vk,
    const float* __restrict__ wsr, const float* __restrict__ gs, const float* __restrict__ bs,
    const float* __restrict__ ms, const float* __restrict__ vs,
    const float* __restrict__ wh1, const float* __restrict__ gh, const float* __restrict__ bh,
    const float* __restrict__ mh, const float* __restrict__ vh,
    f16* __restrict__ wk16, f16* __restrict__ ws16, f16* __restrict__ wh116,
    float* __restrict__ shifts) {
  int o = blockIdx.x;
  int t = threadIdx.x;
  float sck = gk[o] * rsqrtf(vk[o] + 1e-5f);
  float scs = gs[o] * rsqrtf(vs[o] + 1e-5f);
  float sch = gh[o] * rsqrtf(vh[o] + 1e-5f);
  int idx = o * 256 + t;
  wk16[idx]  = (f16)(wk[idx] * sck);
  ws16[idx]  = (f16)(wsr[idx] * scs);
  wh116[idx] = (f16)(wh1[idx] * sch);
  if (t == 0) {
    shifts[o]       = bk[o] - mk[o] * sck;
    shifts[256 + o] = bs[o] - ms[o] * scs;
    shifts[512 + o] = bh[o] - mh[o] * sch;
  }
}

// ---------------- conv1x1 + BN + ReLU, fp32 NCHW input -> f16 [N][256] channels-last ----
// out[n][o] = relu( sum_c W16[o][c] * X[b, c, p] + shift[o] ),  n = b*P + p
// grid: (4 o-blocks, N/64 n-blocks), block 256 (4 waves, 2x2 of 32x32 per wave)
__global__ __launch_bounds__(256) void conv_bn_relu_f32in(
    const float* __restrict__ X, const f16* __restrict__ W,
    const float* __restrict__ shift, f16* __restrict__ out,
    int P, int CP /* 256*P */) {
  const int C = 256;
  int o0 = blockIdx.x * 64;
  int n0 = blockIdx.y * 64;
  int t = threadIdx.x;
  int lane = t & 63, wave = t >> 6;
  int wm = (wave >> 1) * 32, wn = (wave & 1) * 32;
  int fm = lane & 15, fk = (lane >> 4) * 8;

  __shared__ f16 Bs[4][64][8];   // [kg][n][e] = X[c0 + kg*8 + e][n0 + n]

  // B staging coords: thread -> (n = t&63, kg = t>>6)
  int b_n = t & 63;
  int b_kg = t >> 6;
  int gn = n0 + b_n;
  int bq = gn / P;
  int bp = gn - bq * P;
  const float* xcol = X + (size_t)bq * CP + bp;

  const f16* wp0 = W + (size_t)(o0 + wm + fm) * C + fk;
  const f16* wp1 = wp0 + 16 * C;

  f32x4 acc[2][2] = {};

  for (int c0 = 0; c0 < C; c0 += 32) {
    // gather 8 strided fp32, convert to f16
    const float* xp = xcol + (size_t)(c0 + b_kg * 8) * P;
    f16x8 bv;
#pragma unroll
    for (int e = 0; e < 8; ++e) bv[e] = (f16)xp[e * P];
    __syncthreads();                       // previous iter's reads done
    *(f16x8*)&Bs[b_kg][b_n][0] = bv;
    __syncthreads();                       // tile visible

    f16x8 a0 = *(const f16x8*)(wp0 + c0);
    f16x8 a1 = *(const f16x8*)(wp1 + c0);
    f16x8 b0 = *(const f16x8*)&Bs[lane >> 4][wn + fm][0];
    f16x8 b1 = *(const f16x8*)&Bs[lane >> 4][wn + 16 + fm][0];
    acc[0][0] = MFMA16(a0, b0, acc[0][0]);
    acc[0][1] = MFMA16(a0, b1, acc[0][1]);
    acc[1][0] = MFMA16(a1, b0, acc[1][0]);
    acc[1][1] = MFMA16(a1, b1, acc[1][1]);
  }

#pragma unroll
  for (int mi = 0; mi < 2; ++mi)
#pragma unroll
    for (int ni = 0; ni < 2; ++ni) {
      int orow = o0 + wm + mi * 16 + (lane >> 4) * 4;
      int ncol = n0 + wn + ni * 16 + (lane & 15);
      f16x4 st;
#pragma unroll
      for (int r = 0; r < 4; ++r) {
        float v = acc[mi][ni][r] + shift[orow + r];
        st[r] = (f16)fmaxf(v, 0.0f);
      }
      *(f16x4*)&out[(size_t)ncol * 256 + orow] = st;
    }
}

// ---------------- conv1x1 + BN + ReLU, f16 [N][256] channels-last input -> same layout ----
// No LDS: both operands k-contiguous in global.
__global__ __launch_bounds__(256) void conv_bn_relu_f16in(
    const f16* __restrict__ Xt /* [N][256] */, const f16* __restrict__ W,
    const float* __restrict__ shift, f16* __restrict__ out) {
  const int C = 256;
  int o0 = blockIdx.x * 64;
  int n0 = blockIdx.y * 64;
  int t = threadIdx.x;
  int lane = t & 63, wave = t >> 6;
  int wm = (wave >> 1) * 32, wn = (wave & 1) * 32;
  int fm = lane & 15, fk = (lane >> 4) * 8;

  const f16* wp0 = W + (size_t)(o0 + wm + fm) * C + fk;
  const f16* wp1 = wp0 + 16 * C;
  const f16* xp0 = Xt + (size_t)(n0 + wn + fm) * C + fk;
  const f16* xp1 = xp0 + 16 * C;

  f32x4 acc[2][2] = {};
#pragma unroll
  for (int c0 = 0; c0 < C; c0 += 32) {
    f16x8 a0 = *(const f16x8*)(wp0 + c0);
    f16x8 a1 = *(const f16x8*)(wp1 + c0);
    f16x8 b0 = *(const f16x8*)(xp0 + c0);
    f16x8 b1 = *(const f16x8*)(xp1 + c0);
    acc[0][0] = MFMA16(a0, b0, acc[0][0]);
    acc[0][1] = MFMA16(a0, b1, acc[0][1]);
    acc[1][0] = MFMA16(a1, b0, acc[1][0]);
    acc[1][1] = MFMA16(a1, b1, acc[1][1]);
  }

#pragma unroll
  for (int mi = 0; mi < 2; ++mi)
#pragma unroll
    for (int ni = 0; ni < 2; ++ni) {
      int orow = o0 + wm + mi * 16 + (lane >> 4) * 4;
      int ncol = n0 + wn + ni * 16 + (lane & 15);
      f16x4 st;
#pragma unroll
      for (int r = 0; r < 4; ++r) {
        float v = acc[mi][ni][r] + shift[orow + r];
        st[r] = (f16)fmaxf(v, 0.0f);
      }
      *(f16x4*)&out[(size_t)ncol * 256 + orow] = st;
    }
}

// ---------------- depthwise xcorr: channels-last, lane = 4 channels ----------------
// F[b, oi, oj, c] = sum_{di,dj} S[b, oi+di, oj+dj, c] * K[b, di, dj, c]
// grid (10 pixel-tiles, 128 b), block 256: wave handles 16 pixels x 256 ch
__global__ __launch_bounds__(256) void xcorr_dw(
    const f16* __restrict__ S /* [128][31][31][256] */,
    const f16* __restrict__ K /* [128][7][7][256] */,
    f16* __restrict__ F /* [128][25][25][256] */) {
  int b = blockIdx.y;
  int t = threadIdx.x;
  int lane = t & 63, wave = t >> 6;
  int p0 = blockIdx.x * 64 + wave * 16;

  const f16* Sb = S + (size_t)b * 961 * 256 + lane * 4;
  const f16* Kb = K + (size_t)b * 49 * 256 + lane * 4;

  int soff[16];
#pragma unroll
  for (int i = 0; i < 16; ++i) {
    int p = p0 + i;
    int pc = p < 625 ? p : 624;
    int oi = pc / 25, oj = pc - oi * 25;
    soff[i] = (oi * 31 + oj) * 256;
  }

  float acc[16][4];
#pragma unroll
  for (int i = 0; i < 16; ++i)
#pragma unroll
    for (int e = 0; e < 4; ++e) acc[i][e] = 0.0f;

  for (int q = 0; q < 49; ++q) {
    int di = q / 7, dj = q - di * 7;
    f16x4 kv = *(const f16x4*)(Kb + q * 256);
    float k0 = (float)kv[0], k1 = (float)kv[1], k2 = (float)kv[2], k3 = (float)kv[3];
    int qoff = (di * 31 + dj) * 256;
#pragma unroll
    for (int i = 0; i < 16; ++i) {
      f16x4 sv = *(const f16x4*)(Sb + soff[i] + qoff);
      acc[i][0] += (float)sv[0] * k0;
      acc[i][1] += (float)sv[1] * k1;
      acc[i][2] += (float)sv[2] * k2;
      acc[i][3] += (float)sv[3] * k3;
    }
  }

  f16* Fb = F + (size_t)b * 625 * 256 + lane * 4;
#pragma unroll
  for (int i = 0; i < 16; ++i) {
    int p = p0 + i;
    if (p < 625) {
      f16x4 o;
#pragma unroll
      for (int e = 0; e < 4; ++e) o[e] = (f16)acc[i][e];
      *(f16x4*)(Fb + (size_t)p * 256) = o;
    }
  }
}

// ---------------- final 1x1 conv: y [N][256] f16 -> out [128][20][625] fp32 ----------------
__global__ __launch_bounds__(256) void head_conv2(
    const f16* __restrict__ Y, const float* __restrict__ W2 /* [20][256] */,
    const float* __restrict__ bias, float* __restrict__ out, int N) {
  int n = blockIdx.x * 256 + threadIdx.x;
  if (n >= N) return;
  const f16* yp = Y + (size_t)n * 256;
  float acc[20];
#pragma unroll
  for (int o = 0; o < 20; ++o) acc[o] = 0.0f;
  for (int c8 = 0; c8 < 32; ++c8) {
    f16x8 yv = *(const f16x8*)(yp + c8 * 8);
#pragma unroll
    for (int e = 0; e < 8; ++e) {
      float yf = (float)yv[e];
      int c = c8 * 8 + e;
#pragma unroll
      for (int o = 0; o < 20; ++o) acc[o] += yf * W2[o * 256 + c];
    }
  }
  int b = n / 625, p = n - b * 625;
  float* op = out + (size_t)b * 12500 + p;
#pragma unroll
  for (int o = 0; o < 20; ++o) op[(size_t)o * 625] = acc[o] + bias[o];
}

extern "C" void kernel_launch(void* const* d_in, const int* in_sizes, int n_in,
                              void* d_out, int out_size, void* d_ws, size_t ws_size,
                              hipStream_t stream) {
  const float* kernel_in = (const float*)d_in[0];   // [128,256,7,7]
  const float* search    = (const float*)d_in[1];   // [128,256,31,31]
  const float* w_k = (const float*)d_in[2];
  const float* g_k = (const float*)d_in[3];
  const float* b_k = (const float*)d_in[4];
  const float* m_k = (const float*)d_in[5];
  const float* v_k = (const float*)d_in[6];
  const float* w_s = (const float*)d_in[7];
  const float* g_s = (const float*)d_in[8];
  const float* b_s = (const float*)d_in[9];
  const float* m_s = (const float*)d_in[10];
  const float* v_s = (const float*)d_in[11];
  const float* w_h1 = (const float*)d_in[12];
  const float* g_h = (const float*)d_in[13];
  const float* b_h = (const float*)d_in[14];
  const float* m_h = (const float*)d_in[15];
  const float* v_h = (const float*)d_in[16];
  const float* w_h2 = (const float*)d_in[17];
  const float* bias_h2 = (const float*)d_in[18];
  float* out = (float*)d_out;

  char* ws = (char*)d_ws;
  f16* wk16  = (f16*)(ws + OFF_WK);
  f16* ws16  = (f16*)(ws + OFF_WS);
  f16* wh116 = (f16*)(ws + OFF_WH1);
  float* shifts = (float*)(ws + OFF_SH);
  f16* sbuf = (f16*)(ws + OFF_S);     // search features [123008][256]
  f16* ybuf = (f16*)(ws + OFF_S);     // head features reuse s space [80000][256]
  f16* kbuf = (f16*)(ws + OFF_KF);    // kernel features [6272][256]
  f16* fbuf = (f16*)(ws + OFF_FEAT);  // xcorr output [80000][256]

  prep_weights<<<256, 256, 0, stream>>>(w_k, g_k, b_k, m_k, v_k,
                                        w_s, g_s, b_s, m_s, v_s,
                                        w_h1, g_h, b_h, m_h, v_h,
                                        wk16, ws16, wh116, shifts);

  // search branch: N = 128*961 = 123008 (1922 tiles of 64)
  conv_bn_relu_f32in<<<dim3(4, 1922), 256, 0, stream>>>(
      search, ws16, shifts + 256, sbuf, 961, 256 * 961);

  // kernel branch: N = 128*49 = 6272 (98 tiles)
  conv_bn_relu_f32in<<<dim3(4, 98), 256, 0, stream>>>(
      kernel_in, wk16, shifts + 0, kbuf, 49, 256 * 49);

  // depthwise xcorr -> feat [128*625][256]
  xcorr_dw<<<dim3(10, 128), 256, 0, stream>>>(sbuf, kbuf, fbuf);

  // head conv1: N = 80000 (1250 tiles)
  conv_bn_relu_f16in<<<dim3(4, 1250), 256, 0, stream>>>(
      fbuf, wh116, shifts + 512, ybuf);

  // head conv2 -> fp32 NCHW out
  head_conv2<<<dim3(313), 256, 0, stream>>>(ybuf, w_h2, bias_h2, out, 80000);
}

// Round 2
// 311.780 us; speedup vs baseline: 1.4249x; 1.4249x over previous
//
#include <hip/hip_runtime.h>
#include <hip/hip_fp16.h>

typedef _Float16 f16;
typedef __attribute__((ext_vector_type(8))) _Float16 f16x8;
typedef __attribute__((ext_vector_type(4))) _Float16 f16x4;
typedef __attribute__((ext_vector_type(4))) float f32x4;

#define MFMA16(a, b, c) __builtin_amdgcn_mfma_f32_16x16x32_f16((a), (b), (c), 0, 0, 0)

// ---------------- workspace layout (bytes) ----------------
#define OFF_WK   0u              // w_k folded, f16 [256][256]   (128 KB)
#define OFF_WS   131072u         // w_s folded, f16 [256][256]
#define OFF_WH1  262144u         // w_h1 folded, f16 [256][256]
#define OFF_SH   393216u         // shifts f32 [3][256]
#define OFF_S    409600u         // s  f16 [128*961][256] (62,980,096 B) ; reused as y [80000][256]
#define OFF_KF   63389696u       // k_feat f16 [128*49][256] (3,211,264 B)
#define OFF_FEAT 66600960u       // feat f16 [128*625][256] (40,960,000 B)

// ---------------- weight prep: fold BN scale, convert to f16 ----------------
__global__ __launch_bounds__(256) void prep_weights(
    const float* __restrict__ wk, const float* __restrict__ gk, const float* __restrict__ bk,
    const float* __restrict__ mk, const float* __restrict__ vk,
    const float* __restrict__ wsr, const float* __restrict__ gs, const float* __restrict__ bs,
    const float* __restrict__ ms, const float* __restrict__ vs,
    const float* __restrict__ wh1, const float* __restrict__ gh, const float* __restrict__ bh,
    const float* __restrict__ mh, const float* __restrict__ vh,
    f16* __restrict__ wk16, f16* __restrict__ ws16, f16* __restrict__ wh116,
    float* __restrict__ shifts) {
  int o = blockIdx.x;
  int t = threadIdx.x;
  float sck = gk[o] * rsqrtf(vk[o] + 1e-5f);
  float scs = gs[o] * rsqrtf(vs[o] + 1e-5f);
  float sch = gh[o] * rsqrtf(vh[o] + 1e-5f);
  int idx = o * 256 + t;
  wk16[idx]  = (f16)(wk[idx] * sck);
  ws16[idx]  = (f16)(wsr[idx] * scs);
  wh116[idx] = (f16)(wh1[idx] * sch);
  if (t == 0) {
    shifts[o]       = bk[o] - mk[o] * sck;
    shifts[256 + o] = bs[o] - ms[o] * scs;
    shifts[512 + o] = bh[o] - mh[o] * sch;
  }
}

// ---------------- conv1x1 + BN + ReLU, fp32 NCHW input -> f16 [N][256] channels-last ----
__global__ __launch_bounds__(256) void conv_bn_relu_f32in(
    const float* __restrict__ X, const f16* __restrict__ W,
    const float* __restrict__ shift, f16* __restrict__ out,
    int P, int CP /* 256*P */) {
  const int C = 256;
  int o0 = blockIdx.x * 64;
  int n0 = blockIdx.y * 64;
  int t = threadIdx.x;
  int lane = t & 63, wave = t >> 6;
  int wm = (wave >> 1) * 32, wn = (wave & 1) * 32;
  int fm = lane & 15, fk = (lane >> 4) * 8;

  __shared__ f16 Bs[4][64][8];   // [kg][n][e] = X[c0 + kg*8 + e][n0 + n]

  int b_n = t & 63;
  int b_kg = t >> 6;
  int gn = n0 + b_n;
  int bq = gn / P;
  int bp = gn - bq * P;
  const float* xcol = X + (size_t)bq * CP + bp;

  const f16* wp0 = W + (size_t)(o0 + wm + fm) * C + fk;
  const f16* wp1 = wp0 + 16 * C;

  f32x4 acc[2][2] = {};

  for (int c0 = 0; c0 < C; c0 += 32) {
    const float* xp = xcol + (size_t)(c0 + b_kg * 8) * P;
    f16x8 bv;
#pragma unroll
    for (int e = 0; e < 8; ++e) bv[e] = (f16)xp[e * P];
    __syncthreads();
    *(f16x8*)&Bs[b_kg][b_n][0] = bv;
    __syncthreads();

    f16x8 a0 = *(const f16x8*)(wp0 + c0);
    f16x8 a1 = *(const f16x8*)(wp1 + c0);
    f16x8 b0 = *(const f16x8*)&Bs[lane >> 4][wn + fm][0];
    f16x8 b1 = *(const f16x8*)&Bs[lane >> 4][wn + 16 + fm][0];
    acc[0][0] = MFMA16(a0, b0, acc[0][0]);
    acc[0][1] = MFMA16(a0, b1, acc[0][1]);
    acc[1][0] = MFMA16(a1, b0, acc[1][0]);
    acc[1][1] = MFMA16(a1, b1, acc[1][1]);
  }

#pragma unroll
  for (int mi = 0; mi < 2; ++mi)
#pragma unroll
    for (int ni = 0; ni < 2; ++ni) {
      int orow = o0 + wm + mi * 16 + (lane >> 4) * 4;
      int ncol = n0 + wn + ni * 16 + (lane & 15);
      f16x4 st;
#pragma unroll
      for (int r = 0; r < 4; ++r) {
        float v = acc[mi][ni][r] + shift[orow + r];
        st[r] = (f16)fmaxf(v, 0.0f);
      }
      *(f16x4*)&out[(size_t)ncol * 256 + orow] = st;
    }
}

// ---------------- conv1x1 + BN + ReLU, f16 [N][256] channels-last input -> same layout ----
__global__ __launch_bounds__(256) void conv_bn_relu_f16in(
    const f16* __restrict__ Xt /* [N][256] */, const f16* __restrict__ W,
    const float* __restrict__ shift, f16* __restrict__ out) {
  const int C = 256;
  int o0 = blockIdx.x * 64;
  int n0 = blockIdx.y * 64;
  int t = threadIdx.x;
  int lane = t & 63, wave = t >> 6;
  int wm = (wave >> 1) * 32, wn = (wave & 1) * 32;
  int fm = lane & 15, fk = (lane >> 4) * 8;

  const f16* wp0 = W + (size_t)(o0 + wm + fm) * C + fk;
  const f16* wp1 = wp0 + 16 * C;
  const f16* xp0 = Xt + (size_t)(n0 + wn + fm) * C + fk;
  const f16* xp1 = xp0 + 16 * C;

  f32x4 acc[2][2] = {};
#pragma unroll
  for (int c0 = 0; c0 < C; c0 += 32) {
    f16x8 a0 = *(const f16x8*)(wp0 + c0);
    f16x8 a1 = *(const f16x8*)(wp1 + c0);
    f16x8 b0 = *(const f16x8*)(xp0 + c0);
    f16x8 b1 = *(const f16x8*)(xp1 + c0);
    acc[0][0] = MFMA16(a0, b0, acc[0][0]);
    acc[0][1] = MFMA16(a0, b1, acc[0][1]);
    acc[1][0] = MFMA16(a1, b0, acc[1][0]);
    acc[1][1] = MFMA16(a1, b1, acc[1][1]);
  }

#pragma unroll
  for (int mi = 0; mi < 2; ++mi)
#pragma unroll
    for (int ni = 0; ni < 2; ++ni) {
      int orow = o0 + wm + mi * 16 + (lane >> 4) * 4;
      int ncol = n0 + wn + ni * 16 + (lane & 15);
      f16x4 st;
#pragma unroll
      for (int r = 0; r < 4; ++r) {
        float v = acc[mi][ni][r] + shift[orow + r];
        st[r] = (f16)fmaxf(v, 0.0f);
      }
      *(f16x4*)&out[(size_t)ncol * 256 + orow] = st;
    }
}

// ---------------- depthwise xcorr, row-per-wave with register reuse ----------------
// wave = (b, oi): lane = 4 channels (64 lanes -> all 256 ch), acc[25] f32x4.
// Per tap-row di: load S row (31 f16x4) + K row (7 f16x4) into regs, then
// 7*25 register-resident mixed FMAs -> load:FMA = 1:18.
// 1D grid, XCD-swizzled so all 7 row-groups of one b share an XCD (S-plane
// = 492 KB -> L2-resident).
__global__ __launch_bounds__(256) void xcorr_dw_row(
    const f16* __restrict__ S /* [128][31][31][256] */,
    const f16* __restrict__ K /* [128][7][7][256] */,
    f16* __restrict__ F /* [128][25][25][256] */) {
  // inverse of id = (b%8) + 8*(g + 7*(b/8)), g in [0,7)
  int id = blockIdx.x;            // 0..895
  int x = id & 7;
  int r = id >> 3;
  int g = r % 7;
  int bq = r / 7;
  int b = bq * 8 + x;

  int wave = threadIdx.x >> 6;
  int lane = threadIdx.x & 63;
  int oi = g * 4 + wave;          // 0..27
  if (oi >= 25) return;

  const f16* Sb = S + (size_t)b * 961 * 256 + lane * 4;
  const f16* Kb = K + (size_t)b * 49 * 256 + lane * 4;

  f32x4 acc[25] = {};

  for (int di = 0; di < 7; ++di) {
    const f16* sp = Sb + (size_t)(oi + di) * 31 * 256;
    f16x4 srow[31];
#pragma unroll
    for (int j = 0; j < 31; ++j) srow[j] = *(const f16x4*)(sp + (size_t)j * 256);
    const f16* kp = Kb + (size_t)di * 7 * 256;
    f16x4 krow[7];
#pragma unroll
    for (int j = 0; j < 7; ++j) krow[j] = *(const f16x4*)(kp + (size_t)j * 256);

#pragma unroll
    for (int dj = 0; dj < 7; ++dj) {
      float k0 = (float)krow[dj][0];
      float k1 = (float)krow[dj][1];
      float k2 = (float)krow[dj][2];
      float k3 = (float)krow[dj][3];
#pragma unroll
      for (int oj = 0; oj < 25; ++oj) {
        f16x4 sv = srow[oj + dj];
        acc[oj][0] += (float)sv[0] * k0;
        acc[oj][1] += (float)sv[1] * k1;
        acc[oj][2] += (float)sv[2] * k2;
        acc[oj][3] += (float)sv[3] * k3;
      }
    }
  }

  f16* Fb = F + ((size_t)b * 625 + (size_t)oi * 25) * 256 + lane * 4;
#pragma unroll
  for (int oj = 0; oj < 25; ++oj) {
    f16x4 o;
#pragma unroll
    for (int e = 0; e < 4; ++e) o[e] = (f16)acc[oj][e];
    *(f16x4*)(Fb + (size_t)oj * 256) = o;
  }
}

// ---------------- final 1x1 conv: y [N][256] f16 -> out [128][20][625] fp32 ----------------
__global__ __launch_bounds__(256) void head_conv2(
    const f16* __restrict__ Y, const float* __restrict__ W2 /* [20][256] */,
    const float* __restrict__ bias, float* __restrict__ out, int N) {
  int n = blockIdx.x * 256 + threadIdx.x;
  if (n >= N) return;
  const f16* yp = Y + (size_t)n * 256;
  float acc[20];
#pragma unroll
  for (int o = 0; o < 20; ++o) acc[o] = 0.0f;
  for (int c8 = 0; c8 < 32; ++c8) {
    f16x8 yv = *(const f16x8*)(yp + c8 * 8);
#pragma unroll
    for (int e = 0; e < 8; ++e) {
      float yf = (float)yv[e];
      int c = c8 * 8 + e;
#pragma unroll
      for (int o = 0; o < 20; ++o) acc[o] += yf * W2[o * 256 + c];
    }
  }
  int b = n / 625, p = n - b * 625;
  float* op = out + (size_t)b * 12500 + p;
#pragma unroll
  for (int o = 0; o < 20; ++o) op[(size_t)o * 625] = acc[o] + bias[o];
}

extern "C" void kernel_launch(void* const* d_in, const int* in_sizes, int n_in,
                              void* d_out, int out_size, void* d_ws, size_t ws_size,
                              hipStream_t stream) {
  const float* kernel_in = (const float*)d_in[0];
  const float* search    = (const float*)d_in[1];
  const float* w_k = (const float*)d_in[2];
  const float* g_k = (const float*)d_in[3];
  const float* b_k = (const float*)d_in[4];
  const float* m_k = (const float*)d_in[5];
  const float* v_k = (const float*)d_in[6];
  const float* w_s = (const float*)d_in[7];
  const float* g_s = (const float*)d_in[8];
  const float* b_s = (const float*)d_in[9];
  const float* m_s = (const float*)d_in[10];
  const float* v_s = (const float*)d_in[11];
  const float* w_h1 = (const float*)d_in[12];
  const float* g_h = (const float*)d_in[13];
  const float* b_h = (const float*)d_in[14];
  const float* m_h = (const float*)d_in[15];
  const float* v_h = (const float*)d_in[16];
  const float* w_h2 = (const float*)d_in[17];
  const float* bias_h2 = (const float*)d_in[18];
  float* out = (float*)d_out;

  char* ws = (char*)d_ws;
  f16* wk16  = (f16*)(ws + OFF_WK);
  f16* ws16  = (f16*)(ws + OFF_WS);
  f16* wh116 = (f16*)(ws + OFF_WH1);
  float* shifts = (float*)(ws + OFF_SH);
  f16* sbuf = (f16*)(ws + OFF_S);
  f16* ybuf = (f16*)(ws + OFF_S);
  f16* kbuf = (f16*)(ws + OFF_KF);
  f16* fbuf = (f16*)(ws + OFF_FEAT);

  prep_weights<<<256, 256, 0, stream>>>(w_k, g_k, b_k, m_k, v_k,
                                        w_s, g_s, b_s, m_s, v_s,
                                        w_h1, g_h, b_h, m_h, v_h,
                                        wk16, ws16, wh116, shifts);

  conv_bn_relu_f32in<<<dim3(4, 1922), 256, 0, stream>>>(
      search, ws16, shifts + 256, sbuf, 961, 256 * 961);

  conv_bn_relu_f32in<<<dim3(4, 98), 256, 0, stream>>>(
      kernel_in, wk16, shifts + 0, kbuf, 49, 256 * 49);

  // depthwise xcorr: 1D swizzled grid, 896 blocks (128 b x 7 row-groups)
  xcorr_dw_row<<<dim3(896), 256, 0, stream>>>(sbuf, kbuf, fbuf);

  conv_bn_relu_f16in<<<dim3(4, 1250), 256, 0, stream>>>(
      fbuf, wh116, shifts + 512, ybuf);

  head_conv2<<<dim3(313), 256, 0, stream>>>(ybuf, w_h2, bias_h2, out, 80000);
}

// Round 3
// 184.006 us; speedup vs baseline: 2.4144x; 1.6944x over previous
//
#include <hip/hip_runtime.h>
#include <hip/hip_fp16.h>

typedef _Float16 f16;
typedef __attribute__((ext_vector_type(8))) _Float16 f16x8;
typedef __attribute__((ext_vector_type(4))) _Float16 f16x4;
typedef __attribute__((ext_vector_type(4))) float f32x4;

#define MFMA16(a, b, c) __builtin_amdgcn_mfma_f32_16x16x32_f16((a), (b), (c), 0, 0, 0)

// ---------------- workspace layout (bytes) ----------------
#define OFF_WK   0u              // w_k folded f16 [256][256]
#define OFF_WS   131072u         // w_s folded f16 [256][256]
#define OFF_WH1  262144u         // w_h1 folded f16 [256][256]
#define OFF_W2P  393216u         // w_h2 padded f16 [32][256]
#define OFF_SH   409600u         // shifts f32 [3][256]
#define OFF_S    412672u         // s feat f16 [123008][256]
#define OFF_KF   63392768u       // k feat f16 [6272][256]
#define OFF_FEAT 66604032u       // xcorr out f16 [80000][256]

// ---------------- weight prep: fold BN scale, convert to f16, pad W2 ----------------
__global__ __launch_bounds__(256) void prep_weights(
    const float* __restrict__ wk, const float* __restrict__ gk, const float* __restrict__ bk,
    const float* __restrict__ mk, const float* __restrict__ vk,
    const float* __restrict__ wsr, const float* __restrict__ gs, const float* __restrict__ bs,
    const float* __restrict__ ms, const float* __restrict__ vs,
    const float* __restrict__ wh1, const float* __restrict__ gh, const float* __restrict__ bh,
    const float* __restrict__ mh, const float* __restrict__ vh,
    const float* __restrict__ wh2,
    f16* __restrict__ wk16, f16* __restrict__ ws16, f16* __restrict__ wh116,
    f16* __restrict__ w2p, float* __restrict__ shifts) {
  int o = blockIdx.x;
  int t = threadIdx.x;
  float sck = gk[o] * rsqrtf(vk[o] + 1e-5f);
  float scs = gs[o] * rsqrtf(vs[o] + 1e-5f);
  float sch = gh[o] * rsqrtf(vh[o] + 1e-5f);
  int idx = o * 256 + t;
  wk16[idx]  = (f16)(wk[idx] * sck);
  ws16[idx]  = (f16)(wsr[idx] * scs);
  wh116[idx] = (f16)(wh1[idx] * sch);
  if (o < 32) w2p[idx] = (o < 20) ? (f16)wh2[idx] : (f16)0;
  if (t == 0) {
    shifts[o]       = bk[o] - mk[o] * sck;
    shifts[256 + o] = bs[o] - ms[o] * scs;
    shifts[512 + o] = bh[o] - mh[o] * sch;
  }
}

// ---------------- conv1x1+BN+ReLU, fp32 NCHW -> f16 [N][256], ALL 256 outputs per block ----
// Block: 256 thr (4 waves). Tile: 64 n x 256 o. Wave w owns o in [w*64, w*64+64).
// X-tile (64 n x 256 c) staged once to LDS chunk-major; X read exactly once from HBM.
__global__ __launch_bounds__(256) void conv_f32_allo(
    const float* __restrict__ X, const f16* __restrict__ W,
    const float* __restrict__ shift, f16* __restrict__ out,
    int P, int CP /* 256*P */) {
  const int C = 256;
  int n0 = blockIdx.x * 64;
  int t = threadIdx.x;
  int lane = t & 63, wave = t >> 6;
  int fm = lane & 15, kg = lane >> 4;

  __shared__ f16 Bs[32][64][8];   // [c8][n][e]: chunk-major, 32 KB

  // ---- stage: thread (n = t&63, cblk = t>>6) loads 64 c values for its n ----
  {
    int n = t & 63;
    int cblk = t >> 6;
    int gn = n0 + n;
    int bq = gn / P, bp = gn - bq * P;
    const float* xcol = X + (size_t)bq * CP + bp;
#pragma unroll
    for (int j = 0; j < 8; ++j) {
      int cbase = cblk * 64 + j * 8;
      const float* xp = xcol + (size_t)cbase * P;
      f16x8 v;
#pragma unroll
      for (int e = 0; e < 8; ++e) v[e] = (f16)xp[(size_t)e * P];
      *(f16x8*)&Bs[cbase >> 3][n][0] = v;
    }
  }
  __syncthreads();

  const f16* wp = W + (size_t)(wave * 64 + fm) * C + kg * 8;

  f32x4 acc[4][4] = {};
#pragma unroll
  for (int c0 = 0; c0 < 256; c0 += 32) {
    f16x8 a[4], b[4];
#pragma unroll
    for (int of = 0; of < 4; ++of) a[of] = *(const f16x8*)(wp + (size_t)of * 16 * C + c0);
#pragma unroll
    for (int nf = 0; nf < 4; ++nf) b[nf] = *(const f16x8*)&Bs[(c0 >> 3) + kg][nf * 16 + fm][0];
#pragma unroll
    for (int of = 0; of < 4; ++of)
#pragma unroll
      for (int nf = 0; nf < 4; ++nf)
        acc[of][nf] = MFMA16(a[of], b[nf], acc[of][nf]);
  }

#pragma unroll
  for (int of = 0; of < 4; ++of) {
    int orow = wave * 64 + of * 16 + kg * 4;
#pragma unroll
    for (int nf = 0; nf < 4; ++nf) {
      int n = n0 + nf * 16 + fm;
      f16x4 st;
#pragma unroll
      for (int r = 0; r < 4; ++r)
        st[r] = (f16)fmaxf(acc[of][nf][r] + shift[orow + r], 0.0f);
      *(f16x4*)&out[(size_t)n * 256 + orow] = st;
    }
  }
}

// ---------------- depthwise xcorr, row-per-wave with register reuse ----------------
__global__ __launch_bounds__(256) void xcorr_dw_row(
    const f16* __restrict__ S /* [128][31][31][256] */,
    const f16* __restrict__ K /* [128][7][7][256] */,
    f16* __restrict__ F /* [128][25][25][256] */) {
  int id = blockIdx.x;            // 0..895, XCD-swizzled
  int x = id & 7;
  int r = id >> 3;
  int g = r % 7;
  int bq = r / 7;
  int b = bq * 8 + x;

  int wave = threadIdx.x >> 6;
  int lane = threadIdx.x & 63;
  int oi = g * 4 + wave;          // 0..27
  if (oi >= 25) return;

  const f16* Sb = S + (size_t)b * 961 * 256 + lane * 4;
  const f16* Kb = K + (size_t)b * 49 * 256 + lane * 4;

  f32x4 acc[25] = {};

  for (int di = 0; di < 7; ++di) {
    const f16* sp = Sb + (size_t)(oi + di) * 31 * 256;
    f16x4 srow[31];
#pragma unroll
    for (int j = 0; j < 31; ++j) srow[j] = *(const f16x4*)(sp + (size_t)j * 256);
    const f16* kp = Kb + (size_t)di * 7 * 256;
    f16x4 krow[7];
#pragma unroll
    for (int j = 0; j < 7; ++j) krow[j] = *(const f16x4*)(kp + (size_t)j * 256);

#pragma unroll
    for (int dj = 0; dj < 7; ++dj) {
      float k0 = (float)krow[dj][0];
      float k1 = (float)krow[dj][1];
      float k2 = (float)krow[dj][2];
      float k3 = (float)krow[dj][3];
#pragma unroll
      for (int oj = 0; oj < 25; ++oj) {
        f16x4 sv = srow[oj + dj];
        acc[oj][0] += (float)sv[0] * k0;
        acc[oj][1] += (float)sv[1] * k1;
        acc[oj][2] += (float)sv[2] * k2;
        acc[oj][3] += (float)sv[3] * k3;
      }
    }
  }

  f16* Fb = F + ((size_t)b * 625 + (size_t)oi * 25) * 256 + lane * 4;
#pragma unroll
  for (int oj = 0; oj < 25; ++oj) {
    f16x4 o;
#pragma unroll
    for (int e = 0; e < 4; ++e) o[e] = (f16)acc[oj][e];
    *(f16x4*)(Fb + (size_t)oj * 256) = o;
  }
}

// ---------------- fused head: conv1(256->256)+BN+ReLU then conv2(256->20)+bias ----------
// Block: 256 thr, tile 64 n. Phase 1: y-tile in regs (B direct from global, read once).
// Phase 2: y via LDS chunk-major, GEMM vs padded W2 [32][256], fp32 NCHW out.
__global__ __launch_bounds__(256) void head_fused(
    const f16* __restrict__ Xt /* feat [80000][256] */,
    const f16* __restrict__ W1, const float* __restrict__ shift,
    const f16* __restrict__ W2p /* [32][256] */, const float* __restrict__ bias,
    float* __restrict__ out /* [128][20][625] */) {
  const int C = 256;
  int n0 = blockIdx.x * 64;
  int t = threadIdx.x;
  int lane = t & 63, wave = t >> 6;
  int fm = lane & 15, kg = lane >> 4;

  __shared__ f16 Ys[32][64][8];   // y-tile chunk-major

  const f16* wp = W1 + (size_t)(wave * 64 + fm) * C + kg * 8;
  const f16* xp = Xt + (size_t)(n0 + fm) * C + kg * 8;

  f32x4 acc[4][4] = {};
#pragma unroll
  for (int c0 = 0; c0 < 256; c0 += 32) {
    f16x8 a[4], b[4];
#pragma unroll
    for (int of = 0; of < 4; ++of) a[of] = *(const f16x8*)(wp + (size_t)of * 16 * C + c0);
#pragma unroll
    for (int nf = 0; nf < 4; ++nf) b[nf] = *(const f16x8*)(xp + (size_t)nf * 16 * C + c0);
#pragma unroll
    for (int of = 0; of < 4; ++of)
#pragma unroll
      for (int nf = 0; nf < 4; ++nf)
        acc[of][nf] = MFMA16(a[of], b[nf], acc[of][nf]);
  }

  // ReLU+shift -> f16 -> LDS chunk-major: Ys[o/8][n][o%8]
#pragma unroll
  for (int of = 0; of < 4; ++of) {
    int orow = wave * 64 + of * 16 + kg * 4;
#pragma unroll
    for (int nf = 0; nf < 4; ++nf) {
      int n = nf * 16 + fm;
      f16x4 st;
#pragma unroll
      for (int r = 0; r < 4; ++r)
        st[r] = (f16)fmaxf(acc[of][nf][r] + shift[orow + r], 0.0f);
      *(f16x4*)&Ys[orow >> 3][n][(kg & 1) * 4] = st;
    }
  }
  __syncthreads();

  // GEMM2: M=32 (20 live), N=64 (wave -> 16 n), K=256
  f32x4 acc2[2] = {};
#pragma unroll
  for (int c0 = 0; c0 < 256; c0 += 32) {
    f16x8 b = *(const f16x8*)&Ys[(c0 >> 3) + kg][wave * 16 + fm][0];
    f16x8 a0 = *(const f16x8*)(W2p + (size_t)fm * C + c0 + kg * 8);
    f16x8 a1 = *(const f16x8*)(W2p + (size_t)(16 + fm) * C + c0 + kg * 8);
    acc2[0] = MFMA16(a0, b, acc2[0]);
    acc2[1] = MFMA16(a1, b, acc2[1]);
  }

  int n = n0 + wave * 16 + fm;
  int bq = n / 625, bp = n - bq * 625;
  float* op = out + (size_t)bq * 12500 + bp;
#pragma unroll
  for (int of = 0; of < 2; ++of) {
#pragma unroll
    for (int r = 0; r < 4; ++r) {
      int o = of * 16 + kg * 4 + r;
      if (o < 20) op[(size_t)o * 625] = acc2[of][r] + bias[o];
    }
  }
}

extern "C" void kernel_launch(void* const* d_in, const int* in_sizes, int n_in,
                              void* d_out, int out_size, void* d_ws, size_t ws_size,
                              hipStream_t stream) {
  const float* kernel_in = (const float*)d_in[0];
  const float* search    = (const float*)d_in[1];
  const float* w_k = (const float*)d_in[2];
  const float* g_k = (const float*)d_in[3];
  const float* b_k = (const float*)d_in[4];
  const float* m_k = (const float*)d_in[5];
  const float* v_k = (const float*)d_in[6];
  const float* w_s = (const float*)d_in[7];
  const float* g_s = (const float*)d_in[8];
  const float* b_s = (const float*)d_in[9];
  const float* m_s = (const float*)d_in[10];
  const float* v_s = (const float*)d_in[11];
  const float* w_h1 = (const float*)d_in[12];
  const float* g_h = (const float*)d_in[13];
  const float* b_h = (const float*)d_in[14];
  const float* m_h = (const float*)d_in[15];
  const float* v_h = (const float*)d_in[16];
  const float* w_h2 = (const float*)d_in[17];
  const float* bias_h2 = (const float*)d_in[18];
  float* out = (float*)d_out;

  char* ws = (char*)d_ws;
  f16* wk16  = (f16*)(ws + OFF_WK);
  f16* ws16  = (f16*)(ws + OFF_WS);
  f16* wh116 = (f16*)(ws + OFF_WH1);
  f16* w2p   = (f16*)(ws + OFF_W2P);
  float* shifts = (float*)(ws + OFF_SH);
  f16* sbuf = (f16*)(ws + OFF_S);
  f16* kbuf = (f16*)(ws + OFF_KF);
  f16* fbuf = (f16*)(ws + OFF_FEAT);

  prep_weights<<<256, 256, 0, stream>>>(w_k, g_k, b_k, m_k, v_k,
                                        w_s, g_s, b_s, m_s, v_s,
                                        w_h1, g_h, b_h, m_h, v_h, w_h2,
                                        wk16, ws16, wh116, w2p, shifts);

  // search branch: 1922 n-tiles, each block does all 256 outputs
  conv_f32_allo<<<dim3(1922), 256, 0, stream>>>(
      search, ws16, shifts + 256, sbuf, 961, 256 * 961);

  // kernel branch: 98 n-tiles
  conv_f32_allo<<<dim3(98), 256, 0, stream>>>(
      kernel_in, wk16, shifts + 0, kbuf, 49, 256 * 49);

  // depthwise xcorr
  xcorr_dw_row<<<dim3(896), 256, 0, stream>>>(sbuf, kbuf, fbuf);

  // fused head: conv1+BN+ReLU+conv2+bias -> fp32 NCHW
  head_fused<<<dim3(1250), 256, 0, stream>>>(
      fbuf, wh116, shifts + 512, w2p, bias_h2, out);
}

// Round 4
// 174.813 us; speedup vs baseline: 2.5413x; 1.0526x over previous
//
#include <hip/hip_runtime.h>
#include <hip/hip_fp16.h>

typedef _Float16 f16;
typedef __attribute__((ext_vector_type(8))) _Float16 f16x8;
typedef __attribute__((ext_vector_type(4))) _Float16 f16x4;
typedef __attribute__((ext_vector_type(4))) float f32x4;

#define MFMA16(a, b, c) __builtin_amdgcn_mfma_f32_16x16x32_f16((a), (b), (c), 0, 0, 0)

// ---------------- workspace layout (bytes) ----------------
#define OFF_WK   0u              // w_k folded f16 [256][256]
#define OFF_WS   131072u         // w_s folded f16 [256][256]
#define OFF_WH1  262144u         // w_h1 folded f16 [256][256]
#define OFF_W2P  393216u         // w_h2 padded f16 [32][256]
#define OFF_SH   409600u         // shifts f32 [3][256]
#define OFF_S    412672u         // s feat f16 [123008][256]
#define OFF_KF   63392768u       // k feat f16 [6272][256]
#define OFF_FEAT 66604032u       // xcorr out f16 [80000][256]

// ---------------- weight prep: fold BN scale, convert to f16, pad W2 ----------------
__global__ __launch_bounds__(256) void prep_weights(
    const float* __restrict__ wk, const float* __restrict__ gk, const float* __restrict__ bk,
    const float* __restrict__ mk, const float* __restrict__ vk,
    const float* __restrict__ wsr, const float* __restrict__ gs, const float* __restrict__ bs,
    const float* __restrict__ ms, const float* __restrict__ vs,
    const float* __restrict__ wh1, const float* __restrict__ gh, const float* __restrict__ bh,
    const float* __restrict__ mh, const float* __restrict__ vh,
    const float* __restrict__ wh2,
    f16* __restrict__ wk16, f16* __restrict__ ws16, f16* __restrict__ wh116,
    f16* __restrict__ w2p, float* __restrict__ shifts) {
  int o = blockIdx.x;
  int t = threadIdx.x;
  float sck = gk[o] * rsqrtf(vk[o] + 1e-5f);
  float scs = gs[o] * rsqrtf(vs[o] + 1e-5f);
  float sch = gh[o] * rsqrtf(vh[o] + 1e-5f);
  int idx = o * 256 + t;
  wk16[idx]  = (f16)(wk[idx] * sck);
  ws16[idx]  = (f16)(wsr[idx] * scs);
  wh116[idx] = (f16)(wh1[idx] * sch);
  if (o < 32) w2p[idx] = (o < 20) ? (f16)wh2[idx] : (f16)0;
  if (t == 0) {
    shifts[o]       = bk[o] - mk[o] * sck;
    shifts[256 + o] = bs[o] - ms[o] * scs;
    shifts[512 + o] = bh[o] - mh[o] * sch;
  }
}

// ---------------- conv1x1+BN+ReLU, fp32 NCHW -> f16 [N][256], all 256 outputs per block ----
// Staging: thread = (4 consecutive pixels, 16 channels) -> 16 independent float4 loads,
// 4x4 register transpose, f16x4 LDS writes. LDS c8-stride padded to 520 elems (banks).
template <int P>
__global__ __launch_bounds__(256, 4) void conv_f32_allo(
    const float* __restrict__ X, const f16* __restrict__ W,
    const float* __restrict__ shift, f16* __restrict__ out) {
  const int C = 256;
  const int CP = C * P;
  const int LDC8 = 520;           // padded c8-row stride in f16 elems (1040 B, 16B-aligned)
  int n0 = blockIdx.x * 64;
  int t = threadIdx.x;
  int lane = t & 63, wave = t >> 6;
  int fm = lane & 15, kg = lane >> 4;

  __shared__ f16 Bs[32 * LDC8];   // [c8][n*8 + e], 33280 B

  // ---- stage: thread -> pixels gn0..gn0+3, channels cb..cb+15 ----
  {
    int n4 = (t >> 4) * 4;        // local pixel base (0..60)
    int cb = (t & 15) * 16;       // channel base
    int gn0 = n0 + n4;
    int bq = gn0 / P;
    int bp = gn0 - bq * P;
    const float* xb = X + (size_t)bq * CP;
    bool safe = (bp + 3 < P);
#pragma unroll
    for (int j = 0; j < 4; ++j) {
      int c0 = cb + j * 4;
      f32x4 col[4];               // col[i][e] = X[c0+i][gn0+e]
      if (safe) {
        const float* xp = xb + (size_t)c0 * P + bp;
#pragma unroll
        for (int i = 0; i < 4; ++i) col[i] = *(const f32x4*)(xp + (size_t)i * P);
      } else {
#pragma unroll
        for (int i = 0; i < 4; ++i)
#pragma unroll
          for (int e = 0; e < 4; ++e) {
            int gn = gn0 + e;
            int bqe = gn / P, bpe = gn - bqe * P;
            col[i][e] = X[(size_t)bqe * CP + (size_t)(c0 + i) * P + bpe];
          }
      }
#pragma unroll
      for (int e = 0; e < 4; ++e) {
        f16x4 v;
        v[0] = (f16)col[0][e]; v[1] = (f16)col[1][e];
        v[2] = (f16)col[2][e]; v[3] = (f16)col[3][e];
        *(f16x4*)&Bs[(c0 >> 3) * LDC8 + (n4 + e) * 8 + (c0 & 4)] = v;
      }
    }
  }
  __syncthreads();

  const f16* wp = W + (size_t)(wave * 64 + fm) * C + kg * 8;

  f32x4 acc[4][4] = {};
#pragma unroll
  for (int c0 = 0; c0 < 256; c0 += 32) {
    f16x8 a[4], b[4];
#pragma unroll
    for (int of = 0; of < 4; ++of) a[of] = *(const f16x8*)(wp + (size_t)of * 16 * C + c0);
#pragma unroll
    for (int nf = 0; nf < 4; ++nf)
      b[nf] = *(const f16x8*)&Bs[((c0 >> 3) + kg) * LDC8 + (nf * 16 + fm) * 8];
#pragma unroll
    for (int of = 0; of < 4; ++of)
#pragma unroll
      for (int nf = 0; nf < 4; ++nf)
        acc[of][nf] = MFMA16(a[of], b[nf], acc[of][nf]);
  }

#pragma unroll
  for (int of = 0; of < 4; ++of) {
    int orow = wave * 64 + of * 16 + kg * 4;
#pragma unroll
    for (int nf = 0; nf < 4; ++nf) {
      int n = n0 + nf * 16 + fm;
      f16x4 st;
#pragma unroll
      for (int r = 0; r < 4; ++r)
        st[r] = (f16)fmaxf(acc[of][nf][r] + shift[orow + r], 0.0f);
      *(f16x4*)&out[(size_t)n * 256 + orow] = st;
    }
  }
}

// ---------------- depthwise xcorr, row-per-wave with register reuse ----------------
__global__ __launch_bounds__(256) void xcorr_dw_row(
    const f16* __restrict__ S /* [128][31][31][256] */,
    const f16* __restrict__ K /* [128][7][7][256] */,
    f16* __restrict__ F /* [128][25][25][256] */) {
  int id = blockIdx.x;            // 0..895, XCD-swizzled
  int x = id & 7;
  int r = id >> 3;
  int g = r % 7;
  int bq = r / 7;
  int b = bq * 8 + x;

  int wave = threadIdx.x >> 6;
  int lane = threadIdx.x & 63;
  int oi = g * 4 + wave;          // 0..27
  if (oi >= 25) return;

  const f16* Sb = S + (size_t)b * 961 * 256 + lane * 4;
  const f16* Kb = K + (size_t)b * 49 * 256 + lane * 4;

  f32x4 acc[25] = {};

  for (int di = 0; di < 7; ++di) {
    const f16* sp = Sb + (size_t)(oi + di) * 31 * 256;
    f16x4 srow[31];
#pragma unroll
    for (int j = 0; j < 31; ++j) srow[j] = *(const f16x4*)(sp + (size_t)j * 256);
    const f16* kp = Kb + (size_t)di * 7 * 256;
    f16x4 krow[7];
#pragma unroll
    for (int j = 0; j < 7; ++j) krow[j] = *(const f16x4*)(kp + (size_t)j * 256);

#pragma unroll
    for (int dj = 0; dj < 7; ++dj) {
      float k0 = (float)krow[dj][0];
      float k1 = (float)krow[dj][1];
      float k2 = (float)krow[dj][2];
      float k3 = (float)krow[dj][3];
#pragma unroll
      for (int oj = 0; oj < 25; ++oj) {
        f16x4 sv = srow[oj + dj];
        acc[oj][0] += (float)sv[0] * k0;
        acc[oj][1] += (float)sv[1] * k1;
        acc[oj][2] += (float)sv[2] * k2;
        acc[oj][3] += (float)sv[3] * k3;
      }
    }
  }

  f16* Fb = F + ((size_t)b * 625 + (size_t)oi * 25) * 256 + lane * 4;
#pragma unroll
  for (int oj = 0; oj < 25; ++oj) {
    f16x4 o;
#pragma unroll
    for (int e = 0; e < 4; ++e) o[e] = (f16)acc[oj][e];
    *(f16x4*)(Fb + (size_t)oj * 256) = o;
  }
}

// ---------------- fused head: conv1(256->256)+BN+ReLU then conv2(256->20)+bias ----------
__global__ __launch_bounds__(256) void head_fused(
    const f16* __restrict__ Xt /* feat [80000][256] */,
    const f16* __restrict__ W1, const float* __restrict__ shift,
    const f16* __restrict__ W2p /* [32][256] */, const float* __restrict__ bias,
    float* __restrict__ out /* [128][20][625] */) {
  const int C = 256;
  int n0 = blockIdx.x * 64;
  int t = threadIdx.x;
  int lane = t & 63, wave = t >> 6;
  int fm = lane & 15, kg = lane >> 4;

  __shared__ f16 Ys[32][64][8];   // y-tile chunk-major

  const f16* wp = W1 + (size_t)(wave * 64 + fm) * C + kg * 8;
  const f16* xp = Xt + (size_t)(n0 + fm) * C + kg * 8;

  f32x4 acc[4][4] = {};
#pragma unroll
  for (int c0 = 0; c0 < 256; c0 += 32) {
    f16x8 a[4], b[4];
#pragma unroll
    for (int of = 0; of < 4; ++of) a[of] = *(const f16x8*)(wp + (size_t)of * 16 * C + c0);
#pragma unroll
    for (int nf = 0; nf < 4; ++nf) b[nf] = *(const f16x8*)(xp + (size_t)nf * 16 * C + c0);
#pragma unroll
    for (int of = 0; of < 4; ++of)
#pragma unroll
      for (int nf = 0; nf < 4; ++nf)
        acc[of][nf] = MFMA16(a[of], b[nf], acc[of][nf]);
  }

#pragma unroll
  for (int of = 0; of < 4; ++of) {
    int orow = wave * 64 + of * 16 + kg * 4;
#pragma unroll
    for (int nf = 0; nf < 4; ++nf) {
      int n = nf * 16 + fm;
      f16x4 st;
#pragma unroll
      for (int r = 0; r < 4; ++r)
        st[r] = (f16)fmaxf(acc[of][nf][r] + shift[orow + r], 0.0f);
      *(f16x4*)&Ys[orow >> 3][n][(kg & 1) * 4] = st;
    }
  }
  __syncthreads();

  // GEMM2: M=32 (20 live), N=64 (wave -> 16 n), K=256
  f32x4 acc2[2] = {};
#pragma unroll
  for (int c0 = 0; c0 < 256; c0 += 32) {
    f16x8 b = *(const f16x8*)&Ys[(c0 >> 3) + kg][wave * 16 + fm][0];
    f16x8 a0 = *(const f16x8*)(W2p + (size_t)fm * C + c0 + kg * 8);
    f16x8 a1 = *(const f16x8*)(W2p + (size_t)(16 + fm) * C + c0 + kg * 8);
    acc2[0] = MFMA16(a0, b, acc2[0]);
    acc2[1] = MFMA16(a1, b, acc2[1]);
  }

  int n = n0 + wave * 16 + fm;
  int bq = n / 625, bp = n - bq * 625;
  float* op = out + (size_t)bq * 12500 + bp;
#pragma unroll
  for (int of = 0; of < 2; ++of) {
#pragma unroll
    for (int r = 0; r < 4; ++r) {
      int o = of * 16 + kg * 4 + r;
      if (o < 20) op[(size_t)o * 625] = acc2[of][r] + bias[o];
    }
  }
}

extern "C" void kernel_launch(void* const* d_in, const int* in_sizes, int n_in,
                              void* d_out, int out_size, void* d_ws, size_t ws_size,
                              hipStream_t stream) {
  const float* kernel_in = (const float*)d_in[0];
  const float* search    = (const float*)d_in[1];
  const float* w_k = (const float*)d_in[2];
  const float* g_k = (const float*)d_in[3];
  const float* b_k = (const float*)d_in[4];
  const float* m_k = (const float*)d_in[5];
  const float* v_k = (const float*)d_in[6];
  const float* w_s = (const float*)d_in[7];
  const float* g_s = (const float*)d_in[8];
  const float* b_s = (const float*)d_in[9];
  const float* m_s = (const float*)d_in[10];
  const float* v_s = (const float*)d_in[11];
  const float* w_h1 = (const float*)d_in[12];
  const float* g_h = (const float*)d_in[13];
  const float* b_h = (const float*)d_in[14];
  const float* m_h = (const float*)d_in[15];
  const float* v_h = (const float*)d_in[16];
  const float* w_h2 = (const float*)d_in[17];
  const float* bias_h2 = (const float*)d_in[18];
  float* out = (float*)d_out;

  char* ws = (char*)d_ws;
  f16* wk16  = (f16*)(ws + OFF_WK);
  f16* ws16  = (f16*)(ws + OFF_WS);
  f16* wh116 = (f16*)(ws + OFF_WH1);
  f16* w2p   = (f16*)(ws + OFF_W2P);
  float* shifts = (float*)(ws + OFF_SH);
  f16* sbuf = (f16*)(ws + OFF_S);
  f16* kbuf = (f16*)(ws + OFF_KF);
  f16* fbuf = (f16*)(ws + OFF_FEAT);

  prep_weights<<<256, 256, 0, stream>>>(w_k, g_k, b_k, m_k, v_k,
                                        w_s, g_s, b_s, m_s, v_s,
                                        w_h1, g_h, b_h, m_h, v_h, w_h2,
                                        wk16, ws16, wh116, w2p, shifts);

  // search branch: 1922 n-tiles, each block does all 256 outputs
  conv_f32_allo<961><<<dim3(1922), 256, 0, stream>>>(
      search, ws16, shifts + 256, sbuf);

  // kernel branch: 98 n-tiles
  conv_f32_allo<49><<<dim3(98), 256, 0, stream>>>(
      kernel_in, wk16, shifts + 0, kbuf);

  // depthwise xcorr
  xcorr_dw_row<<<dim3(896), 256, 0, stream>>>(sbuf, kbuf, fbuf);

  // fused head: conv1+BN+ReLU+conv2+bias -> fp32 NCHW
  head_fused<<<dim3(1250), 256, 0, stream>>>(
      fbuf, wh116, shifts + 512, w2p, bias_h2, out);
}